// Round 1
// baseline (55.822 us; speedup 1.0000x reference)
//
#include <hip/hip_runtime.h>

// SelfAttention: x[4,4096,64] f32; Wq,Wk[64,16]; Wv[64,64]; out[4,4096,64] f32.
// Plan: proj (fp32 VALU) -> bf16 q,k,v^T in d_ws; flash attention with
// mfma_f32_32x32x16_bf16 (swapped: S^T = K*Q^T so softmax rows are lane-local).

#define TSEQ 4096
#define NBATCH 4

typedef __attribute__((ext_vector_type(4)))  float fvec4;
typedef __attribute__((ext_vector_type(16))) float f32x16;
typedef __attribute__((ext_vector_type(4)))  short s16x4;
typedef __attribute__((ext_vector_type(8)))  short s16x8;
typedef __attribute__((ext_vector_type(4)))  int   ivec4;

static __device__ __forceinline__ unsigned short f2bf(float f) {
    unsigned u = __float_as_uint(f);
    u += 0x7FFFu + ((u >> 16) & 1u);   // RNE
    return (unsigned short)(u >> 16);
}

static __device__ __forceinline__ int cvt_pk_bf16(float lo, float hi) {
    int r;
    asm("v_cvt_pk_bf16_f32 %0, %1, %2" : "=v"(r) : "v"(lo), "v"(hi));
    return r;
}

// ---------------------------------------------------------------------------
// Projection: 256 threads -> 64 rows/block, each thread computes 24 of the 96
// outputs (q:16, k:16, v:64) for one row. fp32 accumulate, bf16 store.
// v is stored TRANSPOSED: vt[b][dv][t]  (so attention's V^T LDS stage is linear)
// ---------------------------------------------------------------------------
__global__ __launch_bounds__(256) void proj_kernel(
    const float* __restrict__ x,  const float* __restrict__ Wq,
    const float* __restrict__ Wk, const float* __restrict__ Wv,
    unsigned short* __restrict__ qb, unsigned short* __restrict__ kb,
    unsigned short* __restrict__ vt)
{
    __shared__ float xs[64][68];   // +4 pad: 2-way-max bank aliasing on reads
    __shared__ float ws[64][96];   // [e][ q(16) | k(16) | v(64) ]
    const int tid  = threadIdx.x;
    const int row0 = blockIdx.x * 64;

    #pragma unroll
    for (int i = 0; i < 16; ++i) {
        int idx = i * 256 + tid;
        xs[idx >> 6][idx & 63] = x[(size_t)row0 * 64 + idx];
    }
    #pragma unroll
    for (int i = 0; i < 4; ++i) {
        int idx = i * 256 + tid;
        ws[idx >> 4][idx & 15]        = Wq[idx];
        ws[idx >> 4][16 + (idx & 15)] = Wk[idx];
    }
    #pragma unroll
    for (int i = 0; i < 16; ++i) {
        int idx = i * 256 + tid;
        ws[idx >> 6][32 + (idx & 63)] = Wv[idx];
    }
    __syncthreads();

    const int r  = tid >> 2;
    const int ob = (tid & 3) * 24;
    float acc[24];
    #pragma unroll
    for (int j = 0; j < 24; ++j) acc[j] = 0.f;
    #pragma unroll 8
    for (int e = 0; e < 64; ++e) {
        float xv = xs[r][e];
        #pragma unroll
        for (int j4 = 0; j4 < 6; ++j4) {
            fvec4 w4 = *(const fvec4*)&ws[e][ob + j4 * 4];
            acc[j4*4+0] = fmaf(xv, w4[0], acc[j4*4+0]);
            acc[j4*4+1] = fmaf(xv, w4[1], acc[j4*4+1]);
            acc[j4*4+2] = fmaf(xv, w4[2], acc[j4*4+2]);
            acc[j4*4+3] = fmaf(xv, w4[3], acc[j4*4+3]);
        }
    }
    const int grow = row0 + r;
    const int b    = grow >> 12;          // /4096
    const int tt   = grow & (TSEQ - 1);
    #pragma unroll
    for (int j = 0; j < 24; ++j) {
        int o = ob + j;
        unsigned short h = f2bf(acc[j]);
        if (o < 16)      qb[(size_t)grow * 16 + o] = h;
        else if (o < 32) kb[(size_t)grow * 16 + (o - 16)] = h;
        else             vt[((size_t)(b * 64 + (o - 32))) * TSEQ + tt] = h;
    }
}

// ---------------------------------------------------------------------------
// Flash attention. Block = 4 waves, 32 queries/block (grid 128 x 4).
// Wave w handles KV tiles kt = w, w+4, ... (64 keys each); partial online-
// softmax states merged via LDS at the end.
//
// MFMA 32x32x16 bf16 layouts used (C/D verified per guide m74/m101):
//   D[row][col]: col = lane&31, row = (reg&3) + 8*(reg>>2) + 4*(lane>>5)
//   A[row][k]:   row = lane&31;  B[k][col]: col = lane&31.
// Correctness is slot-paired: Q/K frags use identical slot->dqk assignment;
// P^T B-frag regs (r = slot) pair with V^T A-frag reads at the same key slots,
// so the exact hardware k-grouping cancels out.
// ---------------------------------------------------------------------------
__global__ __launch_bounds__(256) void attn_kernel(
    const unsigned short* __restrict__ qb, const unsigned short* __restrict__ kb,
    const unsigned short* __restrict__ vt, float* __restrict__ out)
{
    __shared__ __align__(16) char vstage[4][8192]; // per-wave V^T tile [64][128B]
    __shared__ float mO[3][64][32];                // merge buffers (waves 1..3)
    __shared__ float mm[3][32];
    __shared__ float ml[3][32];

    const int tid  = threadIdx.x;
    const int w    = tid >> 6;
    const int lane = tid & 63;
    const int col  = lane & 31;
    const int g    = lane >> 5;
    const int q0   = blockIdx.x * 32;
    const int b    = blockIdx.y;
    const int qrow = q0 + col;

    // Q fragment (B operand): Q[qrow][dqk slot], one 16B load
    const s16x8 qf = *(const s16x8*)(qb + ((size_t)(b * TSEQ) + qrow) * 16 + 8 * g);

    f32x16 o0 = (f32x16)0.0f;     // O^T[dv 0..31][q]
    f32x16 o1 = (f32x16)0.0f;     // O^T[dv 32..63][q]
    float m = -3.0e38f, lsum = 0.f;

    const float SC = 0.25f * 1.44269504088896340736f; // 1/sqrt(16) * log2(e)
    const int ntiles = (q0 + 32 + 63) >> 6;
    char* const myv = vstage[w];

    for (int kt = w; kt < ntiles; kt += 4) {
        const int k0 = kt << 6;
        // -- stage V^T tile: 64 dv x 64 keys bf16, XOR-swizzle 16B blocks (G4)
        #pragma unroll
        for (int j = 0; j < 8; ++j) {
            int idx = j * 64 + lane;
            int dv = idx >> 3, c16 = idx & 7;
            ivec4 vd = *(const ivec4*)(vt + ((size_t)(b * 64 + dv)) * TSEQ + k0 + c16 * 8);
            *(ivec4*)(myv + dv * 128 + ((c16 * 16) ^ ((dv & 7) << 4))) = vd;
        }
        // -- S^T = K * Q^T, two 32-key halves
        const unsigned short* kp = kb + ((size_t)(b * TSEQ) + k0 + col) * 16 + 8 * g;
        s16x8 kf0 = *(const s16x8*)(kp);
        s16x8 kf1 = *(const s16x8*)(kp + 32 * 16);
        f32x16 s0 = __builtin_amdgcn_mfma_f32_32x32x16_bf16(kf0, qf, (f32x16)0.0f, 0, 0, 0);
        f32x16 s1 = __builtin_amdgcn_mfma_f32_32x32x16_bf16(kf1, qf, (f32x16)0.0f, 0, 0, 0);
        // -- scale + causal mask (log2 domain). Every tile has key k0 <= qrow,
        //    so the running max is always finite: no all-masked NaN case.
        float sv[32];
        #pragma unroll
        for (int rr = 0; rr < 16; ++rr) {
            const int drow = (rr & 3) + 8 * (rr >> 2) + 4 * g;
            sv[rr]      = (k0 + drow      <= qrow) ? s0[rr] * SC : -3.0e38f;
            sv[16 + rr] = (k0 + 32 + drow <= qrow) ? s1[rr] * SC : -3.0e38f;
        }
        // -- row max: in-lane tree + one cross-half shuffle
        float t[16];
        #pragma unroll
        for (int i = 0; i < 16; ++i) t[i] = fmaxf(sv[i], sv[16 + i]);
        #pragma unroll
        for (int s = 8; s > 0; s >>= 1) {
            #pragma unroll
            for (int i = 0; i < s; ++i) t[i] = fmaxf(t[i], t[i + s]);
        }
        const float smax = fmaxf(t[0], __shfl_xor(t[0], 32));
        const float mnew = fmaxf(m, smax);
        const float corr = exp2f(m - mnew);   // first tile: exp2(-huge) = 0
        m = mnew;
        // -- exponentiate + partial row sum (4 chains for ILP)
        float ps0 = 0.f, ps1 = 0.f, ps2 = 0.f, ps3 = 0.f;
        #pragma unroll
        for (int i = 0; i < 32; i += 4) {
            sv[i]   = exp2f(sv[i]   - mnew); ps0 += sv[i];
            sv[i+1] = exp2f(sv[i+1] - mnew); ps1 += sv[i+1];
            sv[i+2] = exp2f(sv[i+2] - mnew); ps2 += sv[i+2];
            sv[i+3] = exp2f(sv[i+3] - mnew); ps3 += sv[i+3];
        }
        lsum = lsum * corr + ((ps0 + ps1) + (ps2 + ps3));
        o0 *= corr;
        o1 *= corr;
        // -- P -> bf16 words; pw[i] packs score regs (2i, 2i+1)
        int pw[16];
        #pragma unroll
        for (int i = 0; i < 16; ++i) pw[i] = cvt_pk_bf16(sv[2*i], sv[2*i+1]);
        // -- O^T += V^T * P^T  (2 dv-chunks x 4 key-chunks of 16)
        #pragma unroll
        for (int mt = 0; mt < 2; ++mt) {
            const int dv = mt * 32 + col;
            const char* vrow = myv + dv * 128;
            const int swz = (dv & 7) << 4;
            f32x16 oacc = mt ? o1 : o0;
            #pragma unroll
            for (int c = 0; c < 4; ++c) {
                s16x4 alo = *(const s16x4*)(vrow + ((32*c +      8*g) ^ swz));
                s16x4 ahi = *(const s16x4*)(vrow + ((32*c + 16 + 8*g) ^ swz));
                s16x8 af = __builtin_shufflevector(alo, ahi, 0,1,2,3,4,5,6,7);
                union { int w4[4]; s16x8 v; } pu;
                pu.w4[0] = pw[4*c+0]; pu.w4[1] = pw[4*c+1];
                pu.w4[2] = pw[4*c+2]; pu.w4[3] = pw[4*c+3];
                oacc = __builtin_amdgcn_mfma_f32_32x32x16_bf16(af, pu.v, oacc, 0, 0, 0);
            }
            if (mt) o1 = oacc; else o0 = oacc;
        }
    }
    lsum += __shfl_xor(lsum, 32);

    // -- merge the 4 waves' partial states
    if (w > 0) {
        if (g == 0) { mm[w-1][col] = m; ml[w-1][col] = lsum; }
        #pragma unroll
        for (int mt = 0; mt < 2; ++mt) {
            const f32x16 oa = mt ? o1 : o0;
            #pragma unroll
            for (int rr = 0; rr < 16; ++rr) {
                const int dv = mt * 32 + (rr & 3) + 8 * (rr >> 2) + 4 * g;
                mO[w-1][dv][col] = oa[rr];
            }
        }
    }
    __syncthreads();
    if (w == 0) {
        float M = m;
        #pragma unroll
        for (int i = 0; i < 3; ++i) M = fmaxf(M, mm[i][col]);
        const float c0  = exp2f(m - M);
        const float cw0 = exp2f(mm[0][col] - M);
        const float cw1 = exp2f(mm[1][col] - M);
        const float cw2 = exp2f(mm[2][col] - M);
        const float L = lsum * c0 + ml[0][col]*cw0 + ml[1][col]*cw1 + ml[2][col]*cw2;
        const float inv = 1.0f / L;
        float* orow = out + ((size_t)(b * TSEQ) + qrow) * 64;
        #pragma unroll
        for (int mt = 0; mt < 2; ++mt) {
            const f32x16 oa = mt ? o1 : o0;
            #pragma unroll
            for (int rr = 0; rr < 16; ++rr) {
                const int dv = mt * 32 + (rr & 3) + 8 * (rr >> 2) + 4 * g;
                float val = oa[rr] * c0 + mO[0][dv][col]*cw0
                          + mO[1][dv][col]*cw1 + mO[2][dv][col]*cw2;
                orow[dv] = val * inv;
            }
        }
    }
}

// ---------------------------------------------------------------------------
extern "C" void kernel_launch(void* const* d_in, const int* in_sizes, int n_in,
                              void* d_out, int out_size, void* d_ws, size_t ws_size,
                              hipStream_t stream) {
    const float* x  = (const float*)d_in[0];
    const float* Wq = (const float*)d_in[1];
    const float* Wk = (const float*)d_in[2];
    const float* Wv = (const float*)d_in[3];

    // workspace: q (512KiB) | k (512KiB) | v^T (2MiB)  = 3 MiB total
    unsigned short* qb = (unsigned short*)d_ws;
    unsigned short* kb = qb + (size_t)NBATCH * TSEQ * 16;
    unsigned short* vt = kb + (size_t)NBATCH * TSEQ * 16;
    float* out = (float*)d_out;

    proj_kernel<<<dim3((NBATCH * TSEQ) / 64), 256, 0, stream>>>(x, Wq, Wk, Wv, qb, kb, vt);
    attn_kernel<<<dim3(TSEQ / 32, NBATCH), 256, 0, stream>>>(qb, kb, vt, out);
}

// Round 2
// 51.299 us; speedup vs baseline: 1.0882x; 1.0882x over previous
//
#include <hip/hip_runtime.h>

// SelfAttention: x[4,4096,64] f32; Wq,Wk[64,16]; Wv[64,64]; out[4,4096,64] f32.
// proj (fp32 VALU) -> bf16 q (pre-scaled by 1/sqrt(16)*log2e), k, v^T in d_ws;
// flash attention with mfma_f32_32x32x16_bf16 (swapped: S^T = K*Q^T).
// Balance: block p owns q-tile pair (p, 127-p) == exactly 65 KV-tiles/block;
// 8 waves split KV tiles round-robin, merge 8 partials via LDS.
// V^T read directly from global (L2-resident, 3 MB) -- no LDS staging.

#define TSEQ 4096
#define NBATCH 4

typedef __attribute__((ext_vector_type(4)))  float fvec4;
typedef __attribute__((ext_vector_type(16))) float f32x16;
typedef __attribute__((ext_vector_type(4)))  short s16x4;
typedef __attribute__((ext_vector_type(8)))  short s16x8;

static __device__ __forceinline__ unsigned short f2bf(float f) {
    unsigned u = __float_as_uint(f);
    u += 0x7FFFu + ((u >> 16) & 1u);   // RNE
    return (unsigned short)(u >> 16);
}

static __device__ __forceinline__ int cvt_pk_bf16(float lo, float hi) {
    int r;
    asm("v_cvt_pk_bf16_f32 %0, %1, %2" : "=v"(r) : "v"(lo), "v"(hi));
    return r;
}

// ---------------------------------------------------------------------------
// Projection: 256 threads -> 64 rows/block, each thread computes 24 of the 96
// outputs (q:16, k:16, v:64) for one row. fp32 accumulate, bf16 store.
// q is pre-scaled by 1/sqrt(HEAD)*log2(e) so attention softmax runs in exp2
// domain with no per-score multiply. v stored TRANSPOSED: vt[b][dv][t].
// ---------------------------------------------------------------------------
__global__ __launch_bounds__(256) void proj_kernel(
    const float* __restrict__ x,  const float* __restrict__ Wq,
    const float* __restrict__ Wk, const float* __restrict__ Wv,
    unsigned short* __restrict__ qb, unsigned short* __restrict__ kb,
    unsigned short* __restrict__ vt)
{
    __shared__ float xs[64][68];
    __shared__ float ws[64][96];   // [e][ q(16) | k(16) | v(64) ]
    const int tid  = threadIdx.x;
    const int row0 = blockIdx.x * 64;

    #pragma unroll
    for (int i = 0; i < 16; ++i) {
        int idx = i * 256 + tid;
        xs[idx >> 6][idx & 63] = x[(size_t)row0 * 64 + idx];
    }
    #pragma unroll
    for (int i = 0; i < 4; ++i) {
        int idx = i * 256 + tid;
        ws[idx >> 4][idx & 15]        = Wq[idx];
        ws[idx >> 4][16 + (idx & 15)] = Wk[idx];
    }
    #pragma unroll
    for (int i = 0; i < 16; ++i) {
        int idx = i * 256 + tid;
        ws[idx >> 6][32 + (idx & 63)] = Wv[idx];
    }
    __syncthreads();

    const int r  = tid >> 2;
    const int ob = (tid & 3) * 24;
    float acc[24];
    #pragma unroll
    for (int j = 0; j < 24; ++j) acc[j] = 0.f;
    #pragma unroll 8
    for (int e = 0; e < 64; ++e) {
        float xv = xs[r][e];
        #pragma unroll
        for (int j4 = 0; j4 < 6; ++j4) {
            fvec4 w4 = *(const fvec4*)&ws[e][ob + j4 * 4];
            acc[j4*4+0] = fmaf(xv, w4[0], acc[j4*4+0]);
            acc[j4*4+1] = fmaf(xv, w4[1], acc[j4*4+1]);
            acc[j4*4+2] = fmaf(xv, w4[2], acc[j4*4+2]);
            acc[j4*4+3] = fmaf(xv, w4[3], acc[j4*4+3]);
        }
    }
    const float SCQ = 0.25f * 1.44269504088896340736f; // 1/sqrt(16)*log2(e)
    const int grow = row0 + r;
    const int b    = grow >> 12;
    const int tt   = grow & (TSEQ - 1);
    #pragma unroll
    for (int j = 0; j < 24; ++j) {
        int o = ob + j;
        if (o < 16)      qb[(size_t)grow * 16 + o] = f2bf(acc[j] * SCQ);
        else if (o < 32) kb[(size_t)grow * 16 + (o - 16)] = f2bf(acc[j]);
        else             vt[((size_t)(b * 64 + (o - 32))) * TSEQ + tt] = f2bf(acc[j]);
    }
}

// ---------------------------------------------------------------------------
// Flash attention. Block = 8 waves (512 thr), grid (64, 4).
// Block p handles q-tiles A=p and B=127-p sequentially: nA+nB == 65 tiles
// for every p -> perfectly uniform blocks. Wave w does kt = w, w+8, ...
// Partial (m, l, O^T) merged 8-way through LDS, then coalesced f4 stores.
//
// MFMA 32x32x16 bf16: D[row][col]: col=lane&31, row=(reg&3)+8*(reg>>2)+4*(lane>>5)
// A[row][k]: row=lane&31; B[k][col]: col=lane&31. Q/K frags and P/V^T frags are
// slot-paired so the hardware k-grouping cancels.
// ---------------------------------------------------------------------------
__global__ __launch_bounds__(512, 2) void attn_kernel(
    const unsigned short* __restrict__ qb, const unsigned short* __restrict__ kb,
    const unsigned short* __restrict__ vt, float* __restrict__ out)
{
    __shared__ float pm[8][32];
    __shared__ float pl[8][32];
    __shared__ float pO[8][64][33];   // +1 pad: 2-way max on reads/writes

    const int tid  = threadIdx.x;
    const int w    = tid >> 6;
    const int lane = tid & 63;
    const int col  = lane & 31;
    const int g    = lane >> 5;
    const int b    = blockIdx.y;
    const int p    = blockIdx.x;

    // V^T row pointers for this lane's two dv rows (dv = col, col+32)
    const unsigned short* const vrow0 = vt + ((size_t)(b * 64) + col) * TSEQ;
    const unsigned short* const vrow1 = vrow0 + (size_t)32 * TSEQ;

    for (int half = 0; half < 2; ++half) {
        const int i    = half ? (127 - p) : p;
        const int q0   = i * 32;
        const int qrow = q0 + col;
        const int n    = (i + 2) >> 1;        // ceil((q0+32)/64)

        const s16x8 qf = *(const s16x8*)(qb + ((size_t)(b * TSEQ) + qrow) * 16 + 8 * g);

        f32x16 o0 = (f32x16)0.0f;             // O^T[dv 0..31][q]
        f32x16 o1 = (f32x16)0.0f;             // O^T[dv 32..63][q]
        float m = -3.0e38f, lsum = 0.f;

        for (int kt = w; kt < n; kt += 8) {
            const int k0 = kt << 6;
            // -- S^T = K * Q^T (scale pre-folded into q)
            const unsigned short* kp = kb + ((size_t)(b * TSEQ) + k0 + col) * 16 + 8 * g;
            s16x8 kf0 = *(const s16x8*)(kp);
            s16x8 kf1 = *(const s16x8*)(kp + 32 * 16);
            f32x16 s0 = __builtin_amdgcn_mfma_f32_32x32x16_bf16(kf0, qf, (f32x16)0.0f, 0, 0, 0);
            f32x16 s1 = __builtin_amdgcn_mfma_f32_32x32x16_bf16(kf1, qf, (f32x16)0.0f, 0, 0, 0);
            // -- issue V^T fragment loads now (L2-hit); consumed after softmax
            s16x4 va[2][4][2];
            #pragma unroll
            for (int mt = 0; mt < 2; ++mt) {
                const unsigned short* vr = (mt ? vrow1 : vrow0) + k0;
                #pragma unroll
                for (int c = 0; c < 4; ++c) {
                    va[mt][c][0] = *(const s16x4*)(vr + 16 * c + 4 * g);
                    va[mt][c][1] = *(const s16x4*)(vr + 16 * c + 8 + 4 * g);
                }
            }
            // -- causal mask only on the diagonal tile (wave-uniform branch)
            float sv[32];
            if (k0 + 63 <= q0) {
                #pragma unroll
                for (int rr = 0; rr < 16; ++rr) { sv[rr] = s0[rr]; sv[16 + rr] = s1[rr]; }
            } else {
                #pragma unroll
                for (int rr = 0; rr < 16; ++rr) {
                    const int drow = (rr & 3) + 8 * (rr >> 2) + 4 * g;
                    sv[rr]      = (k0 + drow      <= qrow) ? s0[rr] : -3.0e38f;
                    sv[16 + rr] = (k0 + 32 + drow <= qrow) ? s1[rr] : -3.0e38f;
                }
            }
            // -- row max: in-lane tree + one cross-half shuffle
            float t[16];
            #pragma unroll
            for (int j = 0; j < 16; ++j) t[j] = fmaxf(sv[j], sv[16 + j]);
            #pragma unroll
            for (int s = 8; s > 0; s >>= 1) {
                #pragma unroll
                for (int j = 0; j < s; ++j) t[j] = fmaxf(t[j], t[j + s]);
            }
            const float smax = fmaxf(t[0], __shfl_xor(t[0], 32));
            // -- defer-max (T13, THR=8 in log2 domain): skip rescale when safe
            if (!__all(smax <= m + 8.0f)) {
                const float mnew = fmaxf(m, smax);
                const float corr = exp2f(m - mnew);   // first tile: 0
                o0 *= corr; o1 *= corr; lsum *= corr;
                m = mnew;
            }
            // -- exponentiate + partial row sum
            float ps0 = 0.f, ps1 = 0.f, ps2 = 0.f, ps3 = 0.f;
            #pragma unroll
            for (int j = 0; j < 32; j += 4) {
                sv[j]   = exp2f(sv[j]   - m); ps0 += sv[j];
                sv[j+1] = exp2f(sv[j+1] - m); ps1 += sv[j+1];
                sv[j+2] = exp2f(sv[j+2] - m); ps2 += sv[j+2];
                sv[j+3] = exp2f(sv[j+3] - m); ps3 += sv[j+3];
            }
            lsum += (ps0 + ps1) + (ps2 + ps3);
            // -- P -> bf16
            int pw[16];
            #pragma unroll
            for (int j = 0; j < 16; ++j) pw[j] = cvt_pk_bf16(sv[2*j], sv[2*j+1]);
            // -- O^T += V^T * P^T
            #pragma unroll
            for (int mt = 0; mt < 2; ++mt) {
                f32x16 oacc = mt ? o1 : o0;
                #pragma unroll
                for (int c = 0; c < 4; ++c) {
                    s16x8 af = __builtin_shufflevector(va[mt][c][0], va[mt][c][1],
                                                       0,1,2,3,4,5,6,7);
                    union { int w4[4]; s16x8 v; } pu;
                    pu.w4[0] = pw[4*c+0]; pu.w4[1] = pw[4*c+1];
                    pu.w4[2] = pw[4*c+2]; pu.w4[3] = pw[4*c+3];
                    oacc = __builtin_amdgcn_mfma_f32_32x32x16_bf16(af, pu.v, oacc, 0, 0, 0);
                }
                if (mt) o1 = oacc; else o0 = oacc;
            }
        }
        lsum += __shfl_xor(lsum, 32);

        // -- write partials (empty waves write m=-3e38, l=0, O=0: harmless)
        if (g == 0) { pm[w][col] = m; pl[w][col] = lsum; }
        #pragma unroll
        for (int mt = 0; mt < 2; ++mt) {
            const f32x16 oa = mt ? o1 : o0;
            #pragma unroll
            for (int rr = 0; rr < 16; ++rr) {
                const int dv = mt * 32 + (rr & 3) + 8 * (rr >> 2) + 4 * g;
                pO[w][dv][col] = oa[rr];
            }
        }
        __syncthreads();

        // -- 8-way merge, distributed: wave w merges q rows 4w..4w+3,
        //    lane handles (q = 4w + lane>>4, dv = (lane&15)*4 .. +3) -> f4 store
        {
            const int q   = w * 4 + (lane >> 4);
            const int dvb = (lane & 15) * 4;
            float M = pm[0][q];
            #pragma unroll
            for (int ww = 1; ww < 8; ++ww) M = fmaxf(M, pm[ww][q]);
            float L = 0.f, a0 = 0.f, a1 = 0.f, a2 = 0.f, a3 = 0.f;
            #pragma unroll
            for (int ww = 0; ww < 8; ++ww) {
                const float c = exp2f(pm[ww][q] - M);
                L  += c * pl[ww][q];
                a0 += c * pO[ww][dvb + 0][q];
                a1 += c * pO[ww][dvb + 1][q];
                a2 += c * pO[ww][dvb + 2][q];
                a3 += c * pO[ww][dvb + 3][q];
            }
            const float inv = 1.0f / L;
            fvec4 r; r[0] = a0 * inv; r[1] = a1 * inv; r[2] = a2 * inv; r[3] = a3 * inv;
            *(fvec4*)(out + ((size_t)(b * TSEQ) + q0 + q) * 64 + dvb) = r;
        }
        __syncthreads();   // LDS reused by the second q-tile
    }
}

// ---------------------------------------------------------------------------
extern "C" void kernel_launch(void* const* d_in, const int* in_sizes, int n_in,
                              void* d_out, int out_size, void* d_ws, size_t ws_size,
                              hipStream_t stream) {
    const float* x  = (const float*)d_in[0];
    const float* Wq = (const float*)d_in[1];
    const float* Wk = (const float*)d_in[2];
    const float* Wv = (const float*)d_in[3];

    // workspace: q (512KiB) | k (512KiB) | v^T (2MiB)  = 3 MiB total
    unsigned short* qb = (unsigned short*)d_ws;
    unsigned short* kb = qb + (size_t)NBATCH * TSEQ * 16;
    unsigned short* vt = kb + (size_t)NBATCH * TSEQ * 16;
    float* out = (float*)d_out;

    proj_kernel<<<dim3((NBATCH * TSEQ) / 64), 256, 0, stream>>>(x, Wq, Wk, Wv, qb, kb, vt);
    attn_kernel<<<dim3(64, NBATCH), 512, 0, stream>>>(qb, kb, vt, out);
}